// Round 9
// baseline (200.183 us; speedup 1.0000x reference)
//
#include <hip/hip_runtime.h>

#define D 64
#define BM 64         // queries per block (32 per wm-wave-pair)
#define NCHUNK 8      // K split across blocks
#define NLIST (2 * NCHUNK)   // one winner list per (chunk, wn-wave)
#define DECAYF 0.8f
#define OMDF 0.2f
#define EPSF 1e-5f
#define INVS 4.8828125e-4f   // 2^-11

typedef _Float16 f16;
typedef _Float16 f16x8 __attribute__((ext_vector_type(8)));
typedef float f32x4 __attribute__((ext_vector_type(4)));

// ---------- prep: e2[k] (exact fp32) + f16 hi/lo split ----------
__global__ __launch_bounds__(64) void prep_kernel(const float* __restrict__ emb,
    f16* __restrict__ eh, f16* __restrict__ el, float* __restrict__ e2, int K)
{
    int k = blockIdx.x * blockDim.x + threadIdx.x;
    if (k >= K) return;
    const float4* p = reinterpret_cast<const float4*>(emb + (size_t)k * D);
    uint4* ehp = reinterpret_cast<uint4*>(eh + (size_t)k * D);
    uint4* elp = reinterpret_cast<uint4*>(el + (size_t)k * D);
    float s0 = 0.f, s1 = 0.f, s2 = 0.f, s3 = 0.f;
#pragma unroll
    for (int c = 0; c < 8; ++c) {
        float4 a = p[2 * c], b = p[2 * c + 1];
        s0 += a.x * a.x; s1 += a.y * a.y; s2 += a.z * a.z; s3 += a.w * a.w;
        s0 += b.x * b.x; s1 += b.y * b.y; s2 += b.z * b.z; s3 += b.w * b.w;
        float t[8] = {a.x, a.y, a.z, a.w, b.x, b.y, b.z, b.w};
        union { f16 h[8]; uint4 u; } H, L;
#pragma unroll
        for (int j = 0; j < 8; ++j) {
            f16 h = (f16)t[j];
            H.h[j] = h;
            L.h[j] = (f16)((t[j] - (float)h) * 2048.0f);
        }
        ehp[c] = H.u;
        elp[c] = L.u;
    }
    e2[k] = (s0 + s1) + (s2 + s3);
}

// ---------- MFMA 3-pass split-f16, negated-A => t' = 0.5*d2 >= 0 ----------
// 4 waves = 2(wm) x 2(wn), 32 query rows per wave, single-buffered B from L2,
// occupancy-first (<=128 VGPR, 4 waves/SIMD). Packed top-1: uint(t')|tag, min.
__global__ __launch_bounds__(256, 4) void argmin_kernel(
    const float* __restrict__ x, const f16* __restrict__ eh, const f16* __restrict__ el,
    const float* __restrict__ e2, int* __restrict__ pidx, int n, int K)
{
    __shared__ float se2a[1024];     // whole-chunk +0.5*e2 (4KB)

    const int tx   = threadIdx.x;
    const int lane = tx & 63;
    const int wid  = tx >> 6;
    const int wm   = wid >> 1, wn = wid & 1;
    const int lrow = lane & 15;
    const int lkg  = lane >> 4;

    const int chunk = blockIdx.x % NCHUNK;
    const int mblk  = blockIdx.x / NCHUNK;
    const int q0    = mblk * BM;
    const int kc    = K / NCHUNK;    // 1024
    const int k0    = chunk * kc;
    const int NT    = kc / 64;       // 16 tiles of 64 codes

    // ---- A fragments (NEGATED): fp32 x rows -> f16 hi/lo; also f2 per row ----
    f16x8 ah[2][2], al[2][2];
    f32x4 hf2[2];                    // 0.5*f2 for slot rows (m, lkg*4+r)
#pragma unroll
    for (int m = 0; m < 2; ++m) {
        float f2part = 0.f;
#pragma unroll
        for (int ks = 0; ks < 2; ++ks) {
            int row = q0 + wm * 32 + m * 16 + lrow;
            const float4* p = reinterpret_cast<const float4*>(
                x + (size_t)row * D + ks * 32 + lkg * 8);
            float4 va = p[0], vb = p[1];
            float t[8] = {va.x, va.y, va.z, va.w, vb.x, vb.y, vb.z, vb.w};
#pragma unroll
            for (int j = 0; j < 8; ++j) {
                f2part = fmaf(t[j], t[j], f2part);
                float nt = -t[j];
                f16 h = (f16)nt;
                ah[m][ks][j] = h;
                al[m][ks][j] = (f16)((nt - (float)h) * 2048.0f);
            }
        }
        // reduce f2 over the 4 lkg-groups (same lrow)
        f2part += __shfl_xor(f2part, 16, 64);
        f2part += __shfl_xor(f2part, 32, 64);
        // gather 0.5*f2 for this lane's C-slot rows lkg*4 + r
#pragma unroll
        for (int r = 0; r < 4; ++r)
            hf2[m][r] = 0.5f * __shfl(f2part, lkg * 4 + r, 64);
    }

    // ---- whole-chunk e2 table, prescaled by +0.5 ----
    for (int i = tx; i < kc; i += 256) se2a[i] = 0.5f * e2[k0 + i];
    __syncthreads();   // the ONLY barrier

    // ---- lane-constant global fragment offsets (f16 units) ----
    int ofs[2][2];
#pragma unroll
    for (int nf = 0; nf < 2; ++nf)
#pragma unroll
        for (int ks = 0; ks < 2; ++ks)
            ofs[nf][ks] = (wn * 32 + nf * 16 + lrow) * 64 + ks * 32 + lkg * 8;

    // ---- packed top-1 (MINIMIZE uint(t')|tag) per C-slot ----
    unsigned int pbest[8];
#pragma unroll
    for (int s = 0; s < 8; ++s) pbest[s] = 0xFFFFFFFFu;

#pragma unroll 1
    for (int tt = 0; tt < NT; ++tt) {
        const size_t kb = (size_t)(k0 + tt * 64) * 64;
        f16x8 bh[2][2], bl[2][2];
#pragma unroll
        for (int nf = 0; nf < 2; ++nf)
#pragma unroll
            for (int ks = 0; ks < 2; ++ks) {
                bh[nf][ks] = *reinterpret_cast<const f16x8*>(eh + kb + ofs[nf][ks]);
                bl[nf][ks] = *reinterpret_cast<const f16x8*>(el + kb + ofs[nf][ks]);
            }
        const float he0 = se2a[tt * 64 + wn * 32 + lrow];
        const float he1 = se2a[tt * 64 + wn * 32 + 16 + lrow];
        const unsigned int tagA = (unsigned int)(tt * 2);
        const unsigned int tagB = tagA + 1u;

#pragma unroll
        for (int m = 0; m < 2; ++m) {
            f32x4 hh0 = hf2[m] + he0;        // init = 0.5*e2 + 0.5*f2
            f32x4 hh1 = hf2[m] + he1;
            f32x4 md0 = {0.f, 0.f, 0.f, 0.f};
            f32x4 md1 = {0.f, 0.f, 0.f, 0.f};
            hh0 = __builtin_amdgcn_mfma_f32_16x16x32_f16(ah[m][0], bh[0][0], hh0, 0, 0, 0);
            hh1 = __builtin_amdgcn_mfma_f32_16x16x32_f16(ah[m][0], bh[1][0], hh1, 0, 0, 0);
            hh0 = __builtin_amdgcn_mfma_f32_16x16x32_f16(ah[m][1], bh[0][1], hh0, 0, 0, 0);
            hh1 = __builtin_amdgcn_mfma_f32_16x16x32_f16(ah[m][1], bh[1][1], hh1, 0, 0, 0);
            md0 = __builtin_amdgcn_mfma_f32_16x16x32_f16(al[m][0], bh[0][0], md0, 0, 0, 0);
            md1 = __builtin_amdgcn_mfma_f32_16x16x32_f16(al[m][0], bh[1][0], md1, 0, 0, 0);
            md0 = __builtin_amdgcn_mfma_f32_16x16x32_f16(al[m][1], bh[0][1], md0, 0, 0, 0);
            md1 = __builtin_amdgcn_mfma_f32_16x16x32_f16(al[m][1], bh[1][1], md1, 0, 0, 0);
            md0 = __builtin_amdgcn_mfma_f32_16x16x32_f16(ah[m][0], bl[0][0], md0, 0, 0, 0);
            md1 = __builtin_amdgcn_mfma_f32_16x16x32_f16(ah[m][0], bl[1][0], md1, 0, 0, 0);
            md0 = __builtin_amdgcn_mfma_f32_16x16x32_f16(ah[m][1], bl[0][1], md0, 0, 0, 0);
            md1 = __builtin_amdgcn_mfma_f32_16x16x32_f16(ah[m][1], bl[1][1], md1, 0, 0, 0);
#pragma unroll
            for (int r = 0; r < 4; ++r) {
                float tA = fmaf(md0[r], INVS, hh0[r]);   // 0.5*d2, >= 0
                float tB = fmaf(md1[r], INVS, hh1[r]);
                unsigned int uA = (__float_as_uint(tA) & 0xFFFFFFE0u) | tagA;
                unsigned int uB = (__float_as_uint(tB) & 0xFFFFFFE0u) | tagB;
                unsigned int w = uA < uB ? uA : uB;
                int s = m * 4 + r;
                pbest[s] = pbest[s] < w ? pbest[s] : w;
            }
        }
    }

    // ---- merge across the 16 col-lanes (min packed; tie -> lower code id) ----
#pragma unroll
    for (int s = 0; s < 8; ++s) {
        unsigned int u = pbest[s];
        unsigned int tag = u & 31u;
        int cid = (int)((tag >> 1) << 6) | (int)((tag & 1u) << 4) | (wn << 5) | lrow;
#pragma unroll
        for (int xm = 1; xm < 16; xm <<= 1) {
            unsigned int ou = __shfl_xor(u, xm, 64);
            int          oc = __shfl_xor(cid, xm, 64);
            if (ou < u || (ou == u && oc < cid)) { u = ou; cid = oc; }
        }
        if (lrow == 0) {
            int m = s >> 2, r = s & 3;
            int row = q0 + wm * 32 + m * 16 + lkg * 4 + r;
            pidx[(size_t)(chunk * 2 + wn) * n + row] = k0 + cid;
        }
    }
}

// ---------- exact fp32 re-rank of NLIST candidates ----------
__global__ __launch_bounds__(256) void rerank_kernel(
    const float* __restrict__ x, const float* __restrict__ emb, const float* __restrict__ e2,
    const int* __restrict__ pidx, float* __restrict__ out_ind, int* __restrict__ idxf,
    float* __restrict__ counts, int n)
{
    int q = blockIdx.x * blockDim.x + threadIdx.x;
    if (q >= n) return;
    float4 xr[16];
    const float4* xp = reinterpret_cast<const float4*>(x + (size_t)q * D);
#pragma unroll
    for (int i = 0; i < 16; ++i) xr[i] = xp[i];

    float best = 3.4e38f;
    int   bk   = 0x7fffffff;
#pragma unroll 1
    for (int c = 0; c < NLIST; ++c) {
        int k = pidx[(size_t)c * n + q];
        const float4* ep = reinterpret_cast<const float4*>(emb + (size_t)k * D);
        float a0 = 0.f, a1 = 0.f, a2 = 0.f, a3 = 0.f;
#pragma unroll
        for (int i = 0; i < 16; ++i) {
            float4 e4 = ep[i];
            a0 = fmaf(xr[i].x, e4.x, a0);
            a1 = fmaf(xr[i].y, e4.y, a1);
            a2 = fmaf(xr[i].z, e4.z, a2);
            a3 = fmaf(xr[i].w, e4.w, a3);
        }
        float dot  = (a0 + a1) + (a2 + a3);
        float dist = fmaf(dot, -2.0f, e2[k]);
        if (dist < best || (dist == best && k < bk)) { best = dist; bk = k; }
    }
    out_ind[q] = (float)bk;
    idxf[q]    = bk;
    atomicAdd(counts + bk, 1.0f);
}

// ---------- gather quantize + scatter embed_sum (wave per query) ----------
__global__ void gather_scatter_kernel(const float* __restrict__ x, const float* __restrict__ emb,
                                      const int* __restrict__ idxf, float* __restrict__ quant,
                                      float* __restrict__ embed_sum, int n)
{
    int gid = blockIdx.x * blockDim.x + threadIdx.x;
    int q = gid >> 6;
    int d = gid & 63;
    if (q >= n) return;
    int k = idxf[q];
    quant[(size_t)q * D + d] = emb[(size_t)k * D + d];
    atomicAdd(embed_sum + (size_t)k * D + d, x[(size_t)q * D + d]);
}

// ---------- EMA cluster_size (multi-block) + atomic total ----------
__global__ __launch_bounds__(256) void ema_cs_kernel(const float* __restrict__ cluster_size,
                                                     float* __restrict__ ncs, float* __restrict__ total_ws,
                                                     int K)
{
    int k = blockIdx.x * blockDim.x + threadIdx.x;
    float v = 0.f;
    if (k < K) {
        v = cluster_size[k] * DECAYF + ncs[k] * OMDF;
        ncs[k] = v;
    }
#pragma unroll
    for (int m = 1; m < 64; m <<= 1) v += __shfl_xor(v, m, 64);
    __shared__ float red[4];
    int lane = threadIdx.x & 63, w = threadIdx.x >> 6;
    if (lane == 0) red[w] = v;
    __syncthreads();
    if (threadIdx.x == 0) {
        float t = red[0] + red[1] + red[2] + red[3];
        atomicAdd(total_ws, t);
    }
}

// ---------- EMA embed_avg + normalize (runs last; overwrites eh/el scratch) ----------
__global__ void ema_embed_kernel(const float* __restrict__ embed_avg,
                                 const float* __restrict__ ncs, const float* __restrict__ total_ws,
                                 float* __restrict__ nea, float* __restrict__ enorm, int K)
{
    int gid = blockIdx.x * blockDim.x + threadIdx.x;
    if (gid >= K * D) return;
    int k = gid >> 6;
    float total = total_ws[0];
    float v = embed_avg[gid] * DECAYF + nea[gid] * OMDF;
    nea[gid] = v;
    float c = ncs[k];
    float smoothed = (c + EPSF) / (total + (float)K * EPSF) * total;
    enorm[gid] = v / smoothed;
}

extern "C" void kernel_launch(void* const* d_in, const int* in_sizes, int n_in,
                              void* d_out, int out_size, void* d_ws, size_t ws_size,
                              hipStream_t stream) {
    const float* x            = (const float*)d_in[0];   // [n, 64]
    const float* emb          = (const float*)d_in[1];   // [K, 64]
    const float* cluster_size = (const float*)d_in[2];   // [K]
    const float* embed_avg    = (const float*)d_in[3];   // [K, 64]

    const int n = in_sizes[0] / D;   // 16384
    const int K = in_sizes[1] / D;   // 8192

    // output layout (fp32): quantize | embed_ind | embed_normalized | new_cluster_size | new_embed_avg
    float* out     = (float*)d_out;
    float* quant   = out;                        // n*D
    float* out_ind = quant + (size_t)n * D;      // n
    float* enorm   = out_ind + n;                // K*D  (scratch for eh/el until final kernel)
    float* ncs     = enorm + (size_t)K * D;      // K
    float* nea     = ncs + K;                    // K*D

    f16* eh = reinterpret_cast<f16*>(enorm);     // K*D f16
    f16* el = eh + (size_t)K * D;                // K*D f16

    // workspace: e2 | pidx[NLIST][n] | idxf[n] | total
    float* e2    = (float*)d_ws;                       // K
    int*   pidx  = (int*)(e2 + K);                     // NLIST*n
    int*   idxf  = pidx + (size_t)NLIST * n;           // n
    float* total = (float*)(idxf + n);                 // 1

    hipMemsetAsync(ncs, 0, (size_t)K * sizeof(float), stream);
    hipMemsetAsync(nea, 0, (size_t)K * D * sizeof(float), stream);
    hipMemsetAsync(total, 0, sizeof(float), stream);

    prep_kernel<<<(K + 63) / 64, 64, 0, stream>>>(emb, eh, el, e2, K);
    argmin_kernel<<<(n / BM) * NCHUNK, 256, 0, stream>>>(x, eh, el, e2, pidx, n, K);
    rerank_kernel<<<(n + 255) / 256, 256, 0, stream>>>(x, emb, e2, pidx, out_ind, idxf, ncs, n);
    gather_scatter_kernel<<<((size_t)n * D + 255) / 256, 256, 0, stream>>>(x, emb, idxf, quant, nea, n);
    ema_cs_kernel<<<(K + 255) / 256, 256, 0, stream>>>(cluster_size, ncs, total, K);
    ema_embed_kernel<<<(K * D + 255) / 256, 256, 0, stream>>>(embed_avg, ncs, total, nea, enorm, K);
}

// Round 10
// 138.788 us; speedup vs baseline: 1.4424x; 1.4424x over previous
//
#include <hip/hip_runtime.h>

#define D 64
#define BM 128        // queries per block
#define NCHUNK 8      // K split across blocks
#define NLIST (2 * NCHUNK)   // one winner list per (chunk, wn-wave)
#define DECAYF 0.8f
#define OMDF 0.2f
#define EPSF 1e-5f
#define INVS 4.8828125e-4f   // 2^-11

typedef _Float16 f16;
typedef _Float16 f16x8 __attribute__((ext_vector_type(8)));
typedef float f32x4 __attribute__((ext_vector_type(4)));

// ---------- prep: e2[k] (exact fp32) + f16 hi/lo split ----------
__global__ __launch_bounds__(64) void prep_kernel(const float* __restrict__ emb,
    f16* __restrict__ eh, f16* __restrict__ el, float* __restrict__ e2, int K)
{
    int k = blockIdx.x * blockDim.x + threadIdx.x;
    if (k >= K) return;
    const float4* p = reinterpret_cast<const float4*>(emb + (size_t)k * D);
    uint4* ehp = reinterpret_cast<uint4*>(eh + (size_t)k * D);
    uint4* elp = reinterpret_cast<uint4*>(el + (size_t)k * D);
    float s0 = 0.f, s1 = 0.f, s2 = 0.f, s3 = 0.f;
#pragma unroll
    for (int c = 0; c < 8; ++c) {
        float4 a = p[2 * c], b = p[2 * c + 1];
        s0 += a.x * a.x; s1 += a.y * a.y; s2 += a.z * a.z; s3 += a.w * a.w;
        s0 += b.x * b.x; s1 += b.y * b.y; s2 += b.z * b.z; s3 += b.w * b.w;
        float t[8] = {a.x, a.y, a.z, a.w, b.x, b.y, b.z, b.w};
        union { f16 h[8]; uint4 u; } H, L;
#pragma unroll
        for (int j = 0; j < 8; ++j) {
            f16 h = (f16)t[j];
            H.h[j] = h;
            L.h[j] = (f16)((t[j] - (float)h) * 2048.0f);
        }
        ehp[c] = H.u;
        elp[c] = L.u;
    }
    e2[k] = (s0 + s1) + (s2 + s3);
}

// ---------- MFMA 3-pass split-f16, NO LDS tiles / NO in-loop barriers ----------
// Round-8 structure (best measured): B-fragments straight from L2, register
// double-buffered 2-stage pipeline. Added: s_setprio around MFMA clusters
// (barrier-free kernel => waves drift => scheduler arbitration pays, m191).
__global__ __launch_bounds__(256, 2) void argmin_kernel(
    const float* __restrict__ x, const f16* __restrict__ eh, const f16* __restrict__ el,
    const float* __restrict__ e2, int* __restrict__ pidx, int n, int K)
{
    __shared__ float se2a[1024];     // whole-chunk -0.5*e2 (4KB)

    const int tx   = threadIdx.x;
    const int lane = tx & 63;
    const int wid  = tx >> 6;
    const int wm   = wid >> 1, wn = wid & 1;
    const int lrow = lane & 15;
    const int lkg  = lane >> 4;

    const int chunk = blockIdx.x % NCHUNK;
    const int mblk  = blockIdx.x / NCHUNK;
    const int q0    = mblk * BM;
    const int kc    = K / NCHUNK;    // 1024
    const int k0    = chunk * kc;
    const int NT    = kc / 64;       // 16 tiles of 64 codes

    // ---- A fragments: fp32 x rows -> f16 hi/lo in registers (64 VGPR) ----
    f16x8 ah[4][2], al[4][2];
#pragma unroll
    for (int m = 0; m < 4; ++m)
#pragma unroll
        for (int ks = 0; ks < 2; ++ks) {
            int row = q0 + wm * 64 + m * 16 + lrow;
            const float4* p = reinterpret_cast<const float4*>(
                x + (size_t)row * D + ks * 32 + lkg * 8);
            float4 va = p[0], vb = p[1];
            float t[8] = {va.x, va.y, va.z, va.w, vb.x, vb.y, vb.z, vb.w};
#pragma unroll
            for (int j = 0; j < 8; ++j) {
                f16 h = (f16)t[j];
                ah[m][ks][j] = h;
                al[m][ks][j] = (f16)((t[j] - (float)h) * 2048.0f);
            }
        }

    // ---- whole-chunk e2 table, prescaled by -0.5 ----
    for (int i = tx; i < kc; i += 256) se2a[i] = -0.5f * e2[k0 + i];
    __syncthreads();   // the ONLY barrier

    // ---- lane-constant global fragment offsets (f16 units) ----
    int ofs[2][2];
#pragma unroll
    for (int nf = 0; nf < 2; ++nf)
#pragma unroll
        for (int ks = 0; ks < 2; ++ks)
            ofs[nf][ks] = (wn * 32 + nf * 16 + lrow) * 64 + ks * 32 + lkg * 8;

    // ---- packed top-1 state per C-slot: sortable-uint score | 5-bit tag ----
    unsigned int pbest[16];
#pragma unroll
    for (int s = 0; s < 16; ++s) pbest[s] = 0u;

    auto LOADB = [&](f16x8 (&BH)[2][2], f16x8 (&BL)[2][2], int ttv) {
        const size_t kb = (size_t)(k0 + ttv * 64) * 64;
#pragma unroll
        for (int nf = 0; nf < 2; ++nf)
#pragma unroll
            for (int ks = 0; ks < 2; ++ks) {
                BH[nf][ks] = *reinterpret_cast<const f16x8*>(eh + kb + ofs[nf][ks]);
                BL[nf][ks] = *reinterpret_cast<const f16x8*>(el + kb + ofs[nf][ks]);
            }
    };

    auto COMPUTE = [&](const f16x8 (&BH)[2][2], const f16x8 (&BL)[2][2], int ttv) {
        const float c0 = se2a[ttv * 64 + wn * 32 + lrow];
        const float c1 = se2a[ttv * 64 + wn * 32 + 16 + lrow];
        const unsigned int tagA = (unsigned int)(ttv * 2);
        const unsigned int tagB = tagA + 1u;
#pragma unroll
        for (int m = 0; m < 4; ++m) {
            f32x4 hh0 = {c0, c0, c0, c0}, md0 = {0.f, 0.f, 0.f, 0.f};
            f32x4 hh1 = {c1, c1, c1, c1}, md1 = {0.f, 0.f, 0.f, 0.f};
            __builtin_amdgcn_s_setprio(1);
            hh0 = __builtin_amdgcn_mfma_f32_16x16x32_f16(ah[m][0], BH[0][0], hh0, 0, 0, 0);
            hh1 = __builtin_amdgcn_mfma_f32_16x16x32_f16(ah[m][0], BH[1][0], hh1, 0, 0, 0);
            hh0 = __builtin_amdgcn_mfma_f32_16x16x32_f16(ah[m][1], BH[0][1], hh0, 0, 0, 0);
            hh1 = __builtin_amdgcn_mfma_f32_16x16x32_f16(ah[m][1], BH[1][1], hh1, 0, 0, 0);
            md0 = __builtin_amdgcn_mfma_f32_16x16x32_f16(al[m][0], BH[0][0], md0, 0, 0, 0);
            md1 = __builtin_amdgcn_mfma_f32_16x16x32_f16(al[m][0], BH[1][0], md1, 0, 0, 0);
            md0 = __builtin_amdgcn_mfma_f32_16x16x32_f16(al[m][1], BH[0][1], md0, 0, 0, 0);
            md1 = __builtin_amdgcn_mfma_f32_16x16x32_f16(al[m][1], BH[1][1], md1, 0, 0, 0);
            md0 = __builtin_amdgcn_mfma_f32_16x16x32_f16(ah[m][0], BL[0][0], md0, 0, 0, 0);
            md1 = __builtin_amdgcn_mfma_f32_16x16x32_f16(ah[m][0], BL[1][0], md1, 0, 0, 0);
            md0 = __builtin_amdgcn_mfma_f32_16x16x32_f16(ah[m][1], BL[0][1], md0, 0, 0, 0);
            md1 = __builtin_amdgcn_mfma_f32_16x16x32_f16(ah[m][1], BL[1][1], md1, 0, 0, 0);
            __builtin_amdgcn_s_setprio(0);
#pragma unroll
            for (int r = 0; r < 4; ++r) {
                float sA = fmaf(md0[r], INVS, hh0[r]);
                float sB = fmaf(md1[r], INVS, hh1[r]);
                unsigned int bA = __float_as_uint(sA);
                unsigned int bB = __float_as_uint(sB);
                unsigned int uA = bA ^ (0x80000000u | (unsigned int)((int)bA >> 31));
                unsigned int uB = bB ^ (0x80000000u | (unsigned int)((int)bB >> 31));
                unsigned int wA = (uA & 0xFFFFFFE0u) | tagA;
                unsigned int wB = (uB & 0xFFFFFFE0u) | tagB;
                unsigned int w  = wA > wB ? wA : wB;
                int s = m * 4 + r;
                pbest[s] = pbest[s] > w ? pbest[s] : w;
            }
        }
    };

    // ---- 2-stage register pipeline: load(t+1) overlaps compute(t) ----
    f16x8 bh[2][2], bl[2][2], nh[2][2], nl[2][2];
    LOADB(bh, bl, 0);
#pragma unroll 1
    for (int tt = 0; tt < NT; tt += 2) {
        LOADB(nh, nl, tt + 1);           // NT even: tt+1 < NT always
        COMPUTE(bh, bl, tt);
        if (tt + 2 < NT) LOADB(bh, bl, tt + 2);
        COMPUTE(nh, nl, tt + 1);
    }

    // ---- merge across the 16 col-lanes (argmax packed; tie -> lower code id) ----
#pragma unroll
    for (int s = 0; s < 16; ++s) {
        unsigned int u = pbest[s];
        unsigned int tag = u & 31u;
        int cid = (int)((tag >> 1) << 6) | (int)((tag & 1u) << 4) | (wn << 5) | lrow;
#pragma unroll
        for (int xm = 1; xm < 16; xm <<= 1) {
            unsigned int ou = __shfl_xor(u, xm, 64);
            int          oc = __shfl_xor(cid, xm, 64);
            if (ou > u || (ou == u && oc < cid)) { u = ou; cid = oc; }
        }
        if (lrow == 0) {
            int m = s >> 2, r = s & 3;
            int row = q0 + wm * 64 + m * 16 + lkg * 4 + r;
            pidx[(size_t)(chunk * 2 + wn) * n + row] = k0 + cid;
        }
    }
}

// ---------- fused exact re-rank + quantize + scatter (16 lanes per query) ----------
// 4 queries/wave; lane cl in [0,16) evaluates candidate cl with a full exact
// fp32 dot (same numeric style as the proven rerank), 4-step shfl min-reduce
// with tie->lower k, then the 16 lanes cooperatively write quant and atomics.
__global__ __launch_bounds__(256) void rerank_fused_kernel(
    const float* __restrict__ x, const float* __restrict__ emb, const float* __restrict__ e2,
    const int* __restrict__ pidx, float* __restrict__ out_ind, float* __restrict__ quant,
    float* __restrict__ embed_sum, float* __restrict__ counts, int n)
{
    int tid = blockIdx.x * blockDim.x + threadIdx.x;
    int q  = tid >> 4;
    int cl = tid & 15;
    if (q >= n) return;

    int k = pidx[(size_t)cl * n + q];
    const float4* ep = reinterpret_cast<const float4*>(emb + (size_t)k * D);
    const float4* xp = reinterpret_cast<const float4*>(x + (size_t)q * D);
    float a0 = 0.f, a1 = 0.f, a2 = 0.f, a3 = 0.f;
#pragma unroll
    for (int i = 0; i < 16; ++i) {
        float4 e4 = ep[i];
        float4 x4 = xp[i];              // same addr across the 16-lane group
        a0 = fmaf(x4.x, e4.x, a0);
        a1 = fmaf(x4.y, e4.y, a1);
        a2 = fmaf(x4.z, e4.z, a2);
        a3 = fmaf(x4.w, e4.w, a3);
    }
    float dot  = (a0 + a1) + (a2 + a3);
    float dist = fmaf(dot, -2.0f, e2[k]);
    int   bk   = k;

    // min-reduce over the 16 candidate lanes (tie -> lower code id)
#pragma unroll
    for (int xm = 1; xm < 16; xm <<= 1) {
        float od = __shfl_xor(dist, xm, 64);
        int   ok = __shfl_xor(bk, xm, 64);
        if (od < dist || (od == dist && ok < bk)) { dist = od; bk = ok; }
    }

    // cooperative epilogue: lane cl handles dims [4cl, 4cl+4)
    float4 wf = reinterpret_cast<const float4*>(emb + (size_t)bk * D)[cl];
    reinterpret_cast<float4*>(quant + (size_t)q * D)[cl] = wf;
    float4 xv = xp[cl];
    float* es = embed_sum + (size_t)bk * D + cl * 4;
    atomicAdd(es + 0, xv.x);
    atomicAdd(es + 1, xv.y);
    atomicAdd(es + 2, xv.z);
    atomicAdd(es + 3, xv.w);
    if (cl == 0) {
        out_ind[q] = (float)bk;
        atomicAdd(counts + bk, 1.0f);
    }
}

// ---------- EMA cluster_size (multi-block) + atomic total ----------
__global__ __launch_bounds__(256) void ema_cs_kernel(const float* __restrict__ cluster_size,
                                                     float* __restrict__ ncs, float* __restrict__ total_ws,
                                                     int K)
{
    int k = blockIdx.x * blockDim.x + threadIdx.x;
    float v = 0.f;
    if (k < K) {
        v = cluster_size[k] * DECAYF + ncs[k] * OMDF;
        ncs[k] = v;
    }
#pragma unroll
    for (int m = 1; m < 64; m <<= 1) v += __shfl_xor(v, m, 64);
    __shared__ float red[4];
    int lane = threadIdx.x & 63, w = threadIdx.x >> 6;
    if (lane == 0) red[w] = v;
    __syncthreads();
    if (threadIdx.x == 0) {
        float t = red[0] + red[1] + red[2] + red[3];
        atomicAdd(total_ws, t);
    }
}

// ---------- EMA embed_avg + normalize (runs last; overwrites eh/el scratch) ----------
__global__ void ema_embed_kernel(const float* __restrict__ embed_avg,
                                 const float* __restrict__ ncs, const float* __restrict__ total_ws,
                                 float* __restrict__ nea, float* __restrict__ enorm, int K)
{
    int gid = blockIdx.x * blockDim.x + threadIdx.x;
    if (gid >= K * D) return;
    int k = gid >> 6;
    float total = total_ws[0];
    float v = embed_avg[gid] * DECAYF + nea[gid] * OMDF;
    nea[gid] = v;
    float c = ncs[k];
    float smoothed = (c + EPSF) / (total + (float)K * EPSF) * total;
    enorm[gid] = v / smoothed;
}

extern "C" void kernel_launch(void* const* d_in, const int* in_sizes, int n_in,
                              void* d_out, int out_size, void* d_ws, size_t ws_size,
                              hipStream_t stream) {
    const float* x            = (const float*)d_in[0];   // [n, 64]
    const float* emb          = (const float*)d_in[1];   // [K, 64]
    const float* cluster_size = (const float*)d_in[2];   // [K]
    const float* embed_avg    = (const float*)d_in[3];   // [K, 64]

    const int n = in_sizes[0] / D;   // 16384
    const int K = in_sizes[1] / D;   // 8192

    // output layout (fp32): quantize | embed_ind | embed_normalized | new_cluster_size | new_embed_avg
    float* out     = (float*)d_out;
    float* quant   = out;                        // n*D
    float* out_ind = quant + (size_t)n * D;      // n
    float* enorm   = out_ind + n;                // K*D  (scratch for eh/el until final kernel)
    float* ncs     = enorm + (size_t)K * D;      // K
    float* nea     = ncs + K;                    // K*D

    f16* eh = reinterpret_cast<f16*>(enorm);     // K*D f16
    f16* el = eh + (size_t)K * D;                // K*D f16

    // workspace: e2 | pidx[NLIST][n] | total
    float* e2    = (float*)d_ws;                       // K
    int*   pidx  = (int*)(e2 + K);                     // NLIST*n
    float* total = (float*)(pidx + (size_t)NLIST * n); // 1

    hipMemsetAsync(ncs, 0, (size_t)K * sizeof(float), stream);
    hipMemsetAsync(nea, 0, (size_t)K * D * sizeof(float), stream);
    hipMemsetAsync(total, 0, sizeof(float), stream);

    prep_kernel<<<(K + 63) / 64, 64, 0, stream>>>(emb, eh, el, e2, K);
    argmin_kernel<<<(n / BM) * NCHUNK, 256, 0, stream>>>(x, eh, el, e2, pidx, n, K);
    rerank_fused_kernel<<<(n * 16 + 255) / 256, 256, 0, stream>>>(
        x, emb, e2, pidx, out_ind, quant, nea, ncs, n);
    ema_cs_kernel<<<(K + 255) / 256, 256, 0, stream>>>(cluster_size, ncs, total, K);
    ema_embed_kernel<<<(K * D + 255) / 256, 256, 0, stream>>>(embed_avg, ncs, total, nea, enorm, K);
}

// Round 11
// 119.024 us; speedup vs baseline: 1.6819x; 1.1661x over previous
//
#include <hip/hip_runtime.h>

#define D 64
#define BM 128        // queries per block
#define NCHUNK 8      // K split across blocks
#define NLIST (2 * NCHUNK)   // one winner list per (chunk, wn-wave)
#define DECAYF 0.8f
#define OMDF 0.2f
#define EPSF 1e-5f
#define INVS 4.8828125e-4f   // 2^-11

typedef _Float16 f16;
typedef _Float16 f16x8 __attribute__((ext_vector_type(8)));
typedef float f32x4 __attribute__((ext_vector_type(4)));

// ---------- e2[k] = sum_d emb[k][d]^2 (exact fp32) ----------
__global__ __launch_bounds__(64) void e2_kernel(const float* __restrict__ emb,
                                                float* __restrict__ e2, int K)
{
    int k = blockIdx.x * blockDim.x + threadIdx.x;
    if (k >= K) return;
    const float4* p = reinterpret_cast<const float4*>(emb + (size_t)k * D);
    float s0 = 0.f, s1 = 0.f, s2 = 0.f, s3 = 0.f;
#pragma unroll
    for (int i = 0; i < 16; ++i) {
        float4 v = p[i];
        s0 += v.x * v.x; s1 += v.y * v.y; s2 += v.z * v.z; s3 += v.w * v.w;
    }
    e2[k] = (s0 + s1) + (s2 + s3);
}

// ---------- prep: f16 hi/lo split in FRAGMENT-MAJOR layout ----------
// dst[t] with t = tile*512 + sub*64 + lane encodes emb[k][d0..d0+7] where
// sub=(wn*2+nf)*2+ks, k=tile*64+wn*32+nf*16+(lane&15), d0=ks*32+(lane>>4)*8.
// A wave's MFMA B-fragment load becomes base + sub*1KB + lane*16B: fully
// coalesced (1 contiguous 1KB segment instead of 16 scattered 64B segments).
__global__ __launch_bounds__(256) void prep_frag_kernel(const float* __restrict__ emb,
    f16* __restrict__ eh2, f16* __restrict__ el2, int total)   // total = K*8
{
    int t = blockIdx.x * 256 + threadIdx.x;
    if (t >= total) return;
    int lane = t & 63;
    int sub  = (t >> 6) & 7;
    int tile = t >> 9;
    int wn = sub >> 2, nf = (sub >> 1) & 1, ks = sub & 1;
    int lrow = lane & 15, lkg = lane >> 4;
    int k  = tile * 64 + wn * 32 + nf * 16 + lrow;
    int d0 = ks * 32 + lkg * 8;
    const float4* p = reinterpret_cast<const float4*>(emb + (size_t)k * D + d0);
    float4 a = p[0], b = p[1];
    float v[8] = {a.x, a.y, a.z, a.w, b.x, b.y, b.z, b.w};
    union { f16 h[8]; uint4 u; } H, L;
#pragma unroll
    for (int j = 0; j < 8; ++j) {
        f16 h = (f16)v[j];
        H.h[j] = h;
        L.h[j] = (f16)((v[j] - (float)h) * 2048.0f);
    }
    reinterpret_cast<uint4*>(eh2)[t] = H.u;   // coalesced write
    reinterpret_cast<uint4*>(el2)[t] = L.u;
}

// ---------- MFMA 3-pass split-f16, coalesced fragment loads, no in-loop barriers ----
// Round-8 pipeline structure + round-9 positive-distance packing:
// A negated, acc init 0.5*e2 + 0.5*f2  =>  t' = 0.5*||x-e||^2 >= 0 (uint-monotone).
__global__ __launch_bounds__(256, 2) void argmin_kernel(
    const float* __restrict__ x, const f16* __restrict__ eh2, const f16* __restrict__ el2,
    const float* __restrict__ e2, int* __restrict__ pidx, int n, int K)
{
    __shared__ float se2a[1024];     // whole-chunk +0.5*e2 (4KB)

    const int tx   = threadIdx.x;
    const int lane = tx & 63;
    const int wid  = tx >> 6;
    const int wm   = wid >> 1, wn = wid & 1;
    const int lrow = lane & 15;
    const int lkg  = lane >> 4;

    const int chunk = blockIdx.x % NCHUNK;
    const int mblk  = blockIdx.x / NCHUNK;
    const int q0    = mblk * BM;
    const int kc    = K / NCHUNK;    // 1024
    const int k0    = chunk * kc;
    const int gt0   = chunk * (kc / 64);   // global tile id base
    const int NT    = kc / 64;       // 16 tiles of 64 codes

    // ---- A fragments (NEGATED): fp32 x rows -> f16 hi/lo; also 0.5*f2 per slot ----
    f16x8 ah[4][2], al[4][2];
    f32x4 hf2[4];
#pragma unroll
    for (int m = 0; m < 4; ++m) {
        float f2part = 0.f;
#pragma unroll
        for (int ks = 0; ks < 2; ++ks) {
            int row = q0 + wm * 64 + m * 16 + lrow;
            const float4* p = reinterpret_cast<const float4*>(
                x + (size_t)row * D + ks * 32 + lkg * 8);
            float4 va = p[0], vb = p[1];
            float t[8] = {va.x, va.y, va.z, va.w, vb.x, vb.y, vb.z, vb.w};
#pragma unroll
            for (int j = 0; j < 8; ++j) {
                f2part = fmaf(t[j], t[j], f2part);
                float nt = -t[j];
                f16 h = (f16)nt;
                ah[m][ks][j] = h;
                al[m][ks][j] = (f16)((nt - (float)h) * 2048.0f);
            }
        }
        f2part += __shfl_xor(f2part, 16, 64);
        f2part += __shfl_xor(f2part, 32, 64);
#pragma unroll
        for (int r = 0; r < 4; ++r)
            hf2[m][r] = 0.5f * __shfl(f2part, lkg * 4 + r, 64);
    }

    // ---- whole-chunk e2 table, prescaled by +0.5 ----
    for (int i = tx; i < kc; i += 256) se2a[i] = 0.5f * e2[k0 + i];
    __syncthreads();   // the ONLY barrier

    // ---- packed top-1 (MINIMIZE uint(t')|tag) per C-slot ----
    unsigned int pbest[16];
#pragma unroll
    for (int s = 0; s < 16; ++s) pbest[s] = 0xFFFFFFFFu;

    auto LOADB = [&](f16x8 (&BH)[2][2], f16x8 (&BL)[2][2], int ttv) {
        const f16* bhb = eh2 + ((size_t)(gt0 + ttv) << 12);   // tile*4096 f16
        const f16* blb = el2 + ((size_t)(gt0 + ttv) << 12);
#pragma unroll
        for (int nf = 0; nf < 2; ++nf)
#pragma unroll
            for (int ks = 0; ks < 2; ++ks) {
                int sub = (wn * 2 + nf) * 2 + ks;
                BH[nf][ks] = *reinterpret_cast<const f16x8*>(bhb + sub * 512 + lane * 8);
                BL[nf][ks] = *reinterpret_cast<const f16x8*>(blb + sub * 512 + lane * 8);
            }
    };

    auto COMPUTE = [&](const f16x8 (&BH)[2][2], const f16x8 (&BL)[2][2], int ttv) {
        const float he0 = se2a[ttv * 64 + wn * 32 + lrow];
        const float he1 = se2a[ttv * 64 + wn * 32 + 16 + lrow];
        const unsigned int tagA = (unsigned int)(ttv * 2);
        const unsigned int tagB = tagA + 1u;
#pragma unroll
        for (int m = 0; m < 4; ++m) {
            f32x4 hh0 = hf2[m] + he0;        // init = 0.5*f2 + 0.5*e2
            f32x4 hh1 = hf2[m] + he1;
            f32x4 md0 = {0.f, 0.f, 0.f, 0.f};
            f32x4 md1 = {0.f, 0.f, 0.f, 0.f};
            __builtin_amdgcn_s_setprio(1);
            hh0 = __builtin_amdgcn_mfma_f32_16x16x32_f16(ah[m][0], BH[0][0], hh0, 0, 0, 0);
            hh1 = __builtin_amdgcn_mfma_f32_16x16x32_f16(ah[m][0], BH[1][0], hh1, 0, 0, 0);
            hh0 = __builtin_amdgcn_mfma_f32_16x16x32_f16(ah[m][1], BH[0][1], hh0, 0, 0, 0);
            hh1 = __builtin_amdgcn_mfma_f32_16x16x32_f16(ah[m][1], BH[1][1], hh1, 0, 0, 0);
            md0 = __builtin_amdgcn_mfma_f32_16x16x32_f16(al[m][0], BH[0][0], md0, 0, 0, 0);
            md1 = __builtin_amdgcn_mfma_f32_16x16x32_f16(al[m][0], BH[1][0], md1, 0, 0, 0);
            md0 = __builtin_amdgcn_mfma_f32_16x16x32_f16(al[m][1], BH[0][1], md0, 0, 0, 0);
            md1 = __builtin_amdgcn_mfma_f32_16x16x32_f16(al[m][1], BH[1][1], md1, 0, 0, 0);
            md0 = __builtin_amdgcn_mfma_f32_16x16x32_f16(ah[m][0], BL[0][0], md0, 0, 0, 0);
            md1 = __builtin_amdgcn_mfma_f32_16x16x32_f16(ah[m][0], BL[1][0], md1, 0, 0, 0);
            md0 = __builtin_amdgcn_mfma_f32_16x16x32_f16(ah[m][1], BL[0][1], md0, 0, 0, 0);
            md1 = __builtin_amdgcn_mfma_f32_16x16x32_f16(ah[m][1], BL[1][1], md1, 0, 0, 0);
            __builtin_amdgcn_s_setprio(0);
#pragma unroll
            for (int r = 0; r < 4; ++r) {
                float tA = fmaf(md0[r], INVS, hh0[r]);   // 0.5*d2, >= 0
                float tB = fmaf(md1[r], INVS, hh1[r]);
                unsigned int uA = (__float_as_uint(tA) & 0xFFFFFFE0u) | tagA;
                unsigned int uB = (__float_as_uint(tB) & 0xFFFFFFE0u) | tagB;
                unsigned int w = uA < uB ? uA : uB;
                int s = m * 4 + r;
                pbest[s] = pbest[s] < w ? pbest[s] : w;
            }
        }
    };

    // ---- 2-stage register pipeline: load(t+1) overlaps compute(t) ----
    f16x8 bh[2][2], bl[2][2], nh[2][2], nl[2][2];
    LOADB(bh, bl, 0);
#pragma unroll 1
    for (int tt = 0; tt < NT; tt += 2) {
        LOADB(nh, nl, tt + 1);           // NT even: tt+1 < NT always
        COMPUTE(bh, bl, tt);
        if (tt + 2 < NT) LOADB(bh, bl, tt + 2);
        COMPUTE(nh, nl, tt + 1);
    }

    // ---- merge across the 16 col-lanes (min packed; tie -> lower code id) ----
#pragma unroll
    for (int s = 0; s < 16; ++s) {
        unsigned int u = pbest[s];
        unsigned int tag = u & 31u;
        int cid = (int)((tag >> 1) << 6) | (int)((tag & 1u) << 4) | (wn << 5) | lrow;
#pragma unroll
        for (int xm = 1; xm < 16; xm <<= 1) {
            unsigned int ou = __shfl_xor(u, xm, 64);
            int          oc = __shfl_xor(cid, xm, 64);
            if (ou < u || (ou == u && oc < cid)) { u = ou; cid = oc; }
        }
        if (lrow == 0) {
            int m = s >> 2, r = s & 3;
            int row = q0 + wm * 64 + m * 16 + lkg * 4 + r;
            pidx[(size_t)(chunk * 2 + wn) * n + row] = k0 + cid;
        }
    }
}

// ---------- fused exact re-rank + quantize + scatter (16 lanes per query) ----------
__global__ __launch_bounds__(256) void rerank_fused_kernel(
    const float* __restrict__ x, const float* __restrict__ emb, const float* __restrict__ e2,
    const int* __restrict__ pidx, float* __restrict__ out_ind, float* __restrict__ quant,
    float* __restrict__ embed_sum, float* __restrict__ counts, int n)
{
    int tid = blockIdx.x * blockDim.x + threadIdx.x;
    int q  = tid >> 4;
    int cl = tid & 15;
    if (q >= n) return;

    int k = pidx[(size_t)cl * n + q];
    const float4* ep = reinterpret_cast<const float4*>(emb + (size_t)k * D);
    const float4* xp = reinterpret_cast<const float4*>(x + (size_t)q * D);
    float a0 = 0.f, a1 = 0.f, a2 = 0.f, a3 = 0.f;
#pragma unroll
    for (int i = 0; i < 16; ++i) {
        float4 e4 = ep[i];
        float4 x4 = xp[i];
        a0 = fmaf(x4.x, e4.x, a0);
        a1 = fmaf(x4.y, e4.y, a1);
        a2 = fmaf(x4.z, e4.z, a2);
        a3 = fmaf(x4.w, e4.w, a3);
    }
    float dot  = (a0 + a1) + (a2 + a3);
    float dist = fmaf(dot, -2.0f, e2[k]);
    int   bk   = k;

#pragma unroll
    for (int xm = 1; xm < 16; xm <<= 1) {
        float od = __shfl_xor(dist, xm, 64);
        int   ok = __shfl_xor(bk, xm, 64);
        if (od < dist || (od == dist && ok < bk)) { dist = od; bk = ok; }
    }

    float4 wf = reinterpret_cast<const float4*>(emb + (size_t)bk * D)[cl];
    reinterpret_cast<float4*>(quant + (size_t)q * D)[cl] = wf;
    float4 xv = xp[cl];
    float* es = embed_sum + (size_t)bk * D + cl * 4;
    atomicAdd(es + 0, xv.x);
    atomicAdd(es + 1, xv.y);
    atomicAdd(es + 2, xv.z);
    atomicAdd(es + 3, xv.w);
    if (cl == 0) {
        out_ind[q] = (float)bk;
        atomicAdd(counts + bk, 1.0f);
    }
}

// ---------- EMA cluster_size (multi-block) + atomic total ----------
__global__ __launch_bounds__(256) void ema_cs_kernel(const float* __restrict__ cluster_size,
                                                     float* __restrict__ ncs, float* __restrict__ total_ws,
                                                     int K)
{
    int k = blockIdx.x * blockDim.x + threadIdx.x;
    float v = 0.f;
    if (k < K) {
        v = cluster_size[k] * DECAYF + ncs[k] * OMDF;
        ncs[k] = v;
    }
#pragma unroll
    for (int m = 1; m < 64; m <<= 1) v += __shfl_xor(v, m, 64);
    __shared__ float red[4];
    int lane = threadIdx.x & 63, w = threadIdx.x >> 6;
    if (lane == 0) red[w] = v;
    __syncthreads();
    if (threadIdx.x == 0) {
        float t = red[0] + red[1] + red[2] + red[3];
        atomicAdd(total_ws, t);
    }
}

// ---------- EMA embed_avg + normalize (runs last; overwrites eh2/el2 scratch) ----------
__global__ void ema_embed_kernel(const float* __restrict__ embed_avg,
                                 const float* __restrict__ ncs, const float* __restrict__ total_ws,
                                 float* __restrict__ nea, float* __restrict__ enorm, int K)
{
    int gid = blockIdx.x * blockDim.x + threadIdx.x;
    if (gid >= K * D) return;
    int k = gid >> 6;
    float total = total_ws[0];
    float v = embed_avg[gid] * DECAYF + nea[gid] * OMDF;
    nea[gid] = v;
    float c = ncs[k];
    float smoothed = (c + EPSF) / (total + (float)K * EPSF) * total;
    enorm[gid] = v / smoothed;
}

extern "C" void kernel_launch(void* const* d_in, const int* in_sizes, int n_in,
                              void* d_out, int out_size, void* d_ws, size_t ws_size,
                              hipStream_t stream) {
    const float* x            = (const float*)d_in[0];   // [n, 64]
    const float* emb          = (const float*)d_in[1];   // [K, 64]
    const float* cluster_size = (const float*)d_in[2];   // [K]
    const float* embed_avg    = (const float*)d_in[3];   // [K, 64]

    const int n = in_sizes[0] / D;   // 16384
    const int K = in_sizes[1] / D;   // 8192

    // output layout (fp32): quantize | embed_ind | embed_normalized | new_cluster_size | new_embed_avg
    float* out     = (float*)d_out;
    float* quant   = out;                        // n*D
    float* out_ind = quant + (size_t)n * D;      // n
    float* enorm   = out_ind + n;                // K*D  (scratch for eh2/el2 until final kernel)
    float* ncs     = enorm + (size_t)K * D;      // K
    float* nea     = ncs + K;                    // K*D

    f16* eh2 = reinterpret_cast<f16*>(enorm);    // K*D f16, fragment-major
    f16* el2 = eh2 + (size_t)K * D;              // K*D f16, fragment-major

    // workspace: e2 | pidx[NLIST][n] | total
    float* e2    = (float*)d_ws;                       // K
    int*   pidx  = (int*)(e2 + K);                     // NLIST*n
    float* total = (float*)(pidx + (size_t)NLIST * n); // 1

    hipMemsetAsync(ncs, 0, (size_t)K * sizeof(float), stream);
    hipMemsetAsync(nea, 0, (size_t)K * D * sizeof(float), stream);
    hipMemsetAsync(total, 0, sizeof(float), stream);

    e2_kernel<<<(K + 63) / 64, 64, 0, stream>>>(emb, e2, K);
    prep_frag_kernel<<<(K * 8 + 255) / 256, 256, 0, stream>>>(emb, eh2, el2, K * 8);
    argmin_kernel<<<(n / BM) * NCHUNK, 256, 0, stream>>>(x, eh2, el2, e2, pidx, n, K);
    rerank_fused_kernel<<<(n * 16 + 255) / 256, 256, 0, stream>>>(
        x, emb, e2, pidx, out_ind, quant, nea, ncs, n);
    ema_cs_kernel<<<(K + 255) / 256, 256, 0, stream>>>(cluster_size, ncs, total, K);
    ema_embed_kernel<<<(K * D + 255) / 256, 256, 0, stream>>>(embed_avg, ncs, total, nea, enorm, K);
}